// Round 1
// baseline (2274.064 us; speedup 1.0000x reference)
//
#include <hip/hip_runtime.h>
#include <math.h>

#define IMN 1024
#define IMGSZ (IMN * IMN)
#define NIMG 6
#define EPSV 0.001f
#define BM 128
#define BN 128
#define BK 16
#define LDP 132  // padded LDS leading dim (16B-aligned rows, breaks 4-way conflicts)

// ---------------------------------------------------------------------------
// Gaussian taps: k[i] = exp(-0.5*((i-(ks-1)/2)/sigma)^2), normalized.
// One block per sigma.
__global__ __launch_bounds__(256) void build_taps_k(float* __restrict__ taps) {
  const int kss[3] = {91, 481, 1501};
  const float sig[3] = {15.f, 80.f, 250.f};
  int s = blockIdx.x;
  int ks = kss[s];
  float sigma = sig[s];
  float* t = taps + s * 1536;
  float ctr = (float)(ks - 1) * 0.5f;
  __shared__ float red[256];
  float loc = 0.f;
  for (int i = threadIdx.x; i < ks; i += 256) {
    float x = ((float)i - ctr) / sigma;
    float v = expf(-0.5f * x * x);
    t[i] = v;
    loc += v;
  }
  red[threadIdx.x] = loc;
  __syncthreads();
  for (int o = 128; o > 0; o >>= 1) {
    if (threadIdx.x < o) red[threadIdx.x] += red[threadIdx.x + o];
    __syncthreads();
  }
  float inv = 1.f / red[0];
  for (int i = threadIdx.x; i < ks; i += 256) t[i] *= inv;
}

// ---------------------------------------------------------------------------
// Build blur operator W (and its transpose) for one sigma.
// W[r,j] = sum of taps t where reflect(r + t - p) == j. One block per row r.
__global__ __launch_bounds__(256) void build_w_k(const float* __restrict__ taps, int ks,
                                                 float* __restrict__ W,
                                                 float* __restrict__ Wt) {
  int r = blockIdx.x;
  int p = ks >> 1;
  __shared__ float row[IMN];
  for (int i = threadIdx.x; i < IMN; i += 256) row[i] = 0.f;
  __syncthreads();
  for (int t = threadIdx.x; t < ks; t += 256) {
    int q = r + t - p;
    int j = q < 0 ? -q : (q > IMN - 1 ? 2 * (IMN - 1) - q : q);
    atomicAdd(&row[j], taps[t]);
  }
  __syncthreads();
  for (int i = threadIdx.x; i < IMN; i += 256) {
    float v = row[i];
    W[r * IMN + i] = v;
    Wt[i * IMN + r] = v;
  }
}

// ---------------------------------------------------------------------------
// Pass 1 (vertical blur): T_z = W * clip(img_z).  NN GEMM 1024^3, batched z=0..5.
__global__ __launch_bounds__(256) void gemm_blurV(const float* __restrict__ W,
                                                  const float* __restrict__ inp,
                                                  float* __restrict__ T) {
  __shared__ float As[BK][LDP];
  __shared__ float Bs[BK][LDP];
  int z = blockIdx.z;
  const float* Bg = inp + z * IMGSZ;
  float* Cg = T + z * IMGSZ;
  int bm = blockIdx.y * BM;
  int bn = blockIdx.x * BN;
  int tid = threadIdx.x;
  int tx = tid & 15, ty = tid >> 4;
  float acc[2][2][4][4] = {};
  for (int k0 = 0; k0 < IMN; k0 += BK) {
    float4 av[2], bv[2];
#pragma unroll
    for (int i = 0; i < 2; i++) {
      int v = tid + i * 256;
      int arow = v >> 2, akq = (v & 3) * 4;
      av[i] = *(const float4*)&W[(bm + arow) * IMN + k0 + akq];
      int brow = v >> 5, bnq = (v & 31) * 4;
      bv[i] = *(const float4*)&Bg[(k0 + brow) * IMN + bn + bnq];
    }
    __syncthreads();
#pragma unroll
    for (int i = 0; i < 2; i++) {
      int v = tid + i * 256;
      int arow = v >> 2, akq = (v & 3) * 4;
      As[akq + 0][arow] = av[i].x;
      As[akq + 1][arow] = av[i].y;
      As[akq + 2][arow] = av[i].z;
      As[akq + 3][arow] = av[i].w;
      int brow = v >> 5, bnq = (v & 31) * 4;
      float4 cb;
      cb.x = fminf(fmaxf(bv[i].x, EPSV), 1.f);
      cb.y = fminf(fmaxf(bv[i].y, EPSV), 1.f);
      cb.z = fminf(fmaxf(bv[i].z, EPSV), 1.f);
      cb.w = fminf(fmaxf(bv[i].w, EPSV), 1.f);
      *(float4*)&Bs[brow][bnq] = cb;
    }
    __syncthreads();
#pragma unroll
    for (int kk = 0; kk < BK; kk++) {
      float a[2][4], b[2][4];
      *(float4*)a[0] = *(const float4*)&As[kk][ty * 4];
      *(float4*)a[1] = *(const float4*)&As[kk][ty * 4 + 64];
      *(float4*)b[0] = *(const float4*)&Bs[kk][tx * 4];
      *(float4*)b[1] = *(const float4*)&Bs[kk][tx * 4 + 64];
#pragma unroll
      for (int i = 0; i < 2; i++)
#pragma unroll
        for (int ri = 0; ri < 4; ri++)
#pragma unroll
          for (int j = 0; j < 2; j++)
#pragma unroll
            for (int ci = 0; ci < 4; ci++)
              acc[i][j][ri][ci] = fmaf(a[i][ri], b[j][ci], acc[i][j][ri][ci]);
    }
  }
#pragma unroll
  for (int i = 0; i < 2; i++)
#pragma unroll
    for (int ri = 0; ri < 4; ri++) {
      int row = bm + ty * 4 + i * 64 + ri;
#pragma unroll
      for (int j = 0; j < 2; j++) {
        float4 v = make_float4(acc[i][j][ri][0], acc[i][j][ri][1],
                               acc[i][j][ri][2], acc[i][j][ri][3]);
        *(float4*)&Cg[row * IMN + bn + tx * 4 + j * 64] = v;
      }
    }
}

// ---------------------------------------------------------------------------
// Pass 2 (horizontal blur): Blur_z = T_z * Wt; fused epilogue:
// acc_z += log(clip(img)) - log(max(blur, eps))   (write-fresh when first).
__global__ __launch_bounds__(256) void gemm_blurH(const float* __restrict__ T,
                                                  const float* __restrict__ Wt,
                                                  const float* __restrict__ inp,
                                                  float* __restrict__ accb, int first) {
  __shared__ float As[BK][LDP];
  __shared__ float Bs[BK][LDP];
  int z = blockIdx.z;
  const float* Ag = T + z * IMGSZ;
  int bm = blockIdx.y * BM;
  int bn = blockIdx.x * BN;
  int tid = threadIdx.x;
  int tx = tid & 15, ty = tid >> 4;
  float acc[2][2][4][4] = {};
  for (int k0 = 0; k0 < IMN; k0 += BK) {
    float4 av[2], bv[2];
#pragma unroll
    for (int i = 0; i < 2; i++) {
      int v = tid + i * 256;
      int arow = v >> 2, akq = (v & 3) * 4;
      av[i] = *(const float4*)&Ag[(bm + arow) * IMN + k0 + akq];
      int brow = v >> 5, bnq = (v & 31) * 4;
      bv[i] = *(const float4*)&Wt[(k0 + brow) * IMN + bn + bnq];
    }
    __syncthreads();
#pragma unroll
    for (int i = 0; i < 2; i++) {
      int v = tid + i * 256;
      int arow = v >> 2, akq = (v & 3) * 4;
      As[akq + 0][arow] = av[i].x;
      As[akq + 1][arow] = av[i].y;
      As[akq + 2][arow] = av[i].z;
      As[akq + 3][arow] = av[i].w;
      int brow = v >> 5, bnq = (v & 31) * 4;
      *(float4*)&Bs[brow][bnq] = bv[i];
    }
    __syncthreads();
#pragma unroll
    for (int kk = 0; kk < BK; kk++) {
      float a[2][4], b[2][4];
      *(float4*)a[0] = *(const float4*)&As[kk][ty * 4];
      *(float4*)a[1] = *(const float4*)&As[kk][ty * 4 + 64];
      *(float4*)b[0] = *(const float4*)&Bs[kk][tx * 4];
      *(float4*)b[1] = *(const float4*)&Bs[kk][tx * 4 + 64];
#pragma unroll
      for (int i = 0; i < 2; i++)
#pragma unroll
        for (int ri = 0; ri < 4; ri++)
#pragma unroll
          for (int j = 0; j < 2; j++)
#pragma unroll
            for (int ci = 0; ci < 4; ci++)
              acc[i][j][ri][ci] = fmaf(a[i][ri], b[j][ci], acc[i][j][ri][ci]);
    }
  }
#pragma unroll
  for (int i = 0; i < 2; i++)
#pragma unroll
    for (int ri = 0; ri < 4; ri++) {
      int row = bm + ty * 4 + i * 64 + ri;
#pragma unroll
      for (int j = 0; j < 2; j++) {
        int col = bn + tx * 4 + j * 64;
        int g = z * IMGSZ + row * IMN + col;
        float4 iv = *(const float4*)&inp[g];
        float4 r;
        r.x = logf(fminf(fmaxf(iv.x, EPSV), 1.f)) - logf(fmaxf(acc[i][j][ri][0], EPSV));
        r.y = logf(fminf(fmaxf(iv.y, EPSV), 1.f)) - logf(fmaxf(acc[i][j][ri][1], EPSV));
        r.z = logf(fminf(fmaxf(iv.z, EPSV), 1.f)) - logf(fmaxf(acc[i][j][ri][2], EPSV));
        r.w = logf(fminf(fmaxf(iv.w, EPSV), 1.f)) - logf(fmaxf(acc[i][j][ri][3], EPSV));
        if (!first) {
          float4 pa = *(const float4*)&accb[g];
          r.x += pa.x; r.y += pa.y; r.z += pa.z; r.w += pa.w;
        }
        *(float4*)&accb[g] = r;
      }
    }
}

// ---------------------------------------------------------------------------
// Loss reduction: reflectance R = acc/3, illumination I = log(max(in,eps)) - R.
// loss_detail = mean|gx_R| + mean|gy_R|; loss_smooth = mean|gx_I| + mean|gy_I|.
__global__ __launch_bounds__(256) void loss_k(const float* __restrict__ inp,
                                              const float* __restrict__ acc,
                                              float* __restrict__ out) {
  int idx = blockIdx.x * 256 + threadIdx.x;
  float sd = 0.f, ss = 0.f;
  {
    int c = idx & (IMN - 1);
    int rr = (idx >> 10) & (IMN - 1);
    float R0 = acc[idx] * (1.f / 3.f);
    float I0 = logf(fmaxf(inp[idx], EPSV)) - R0;
    if (c < IMN - 1) {
      float R1 = acc[idx + 1] * (1.f / 3.f);
      float I1 = logf(fmaxf(inp[idx + 1], EPSV)) - R1;
      sd += fabsf(R0 - R1);
      ss += fabsf(I0 - I1);
    }
    if (rr < IMN - 1) {
      float R2 = acc[idx + IMN] * (1.f / 3.f);
      float I2 = logf(fmaxf(inp[idx + IMN], EPSV)) - R2;
      sd += fabsf(R0 - R2);
      ss += fabsf(I0 - I2);
    }
  }
  for (int o = 32; o > 0; o >>= 1) {
    sd += __shfl_down(sd, o);
    ss += __shfl_down(ss, o);
  }
  __shared__ float rsd[4], rss[4];
  int lane = threadIdx.x & 63, w = threadIdx.x >> 6;
  if (lane == 0) { rsd[w] = sd; rss[w] = ss; }
  __syncthreads();
  if (threadIdx.x == 0) {
    float tsd = rsd[0] + rsd[1] + rsd[2] + rsd[3];
    float tss = rss[0] + rss[1] + rss[2] + rss[3];
    const float sc = 1.f / 6285312.f;  // 2*3*1024*1023 (same count for gx and gy)
    atomicAdd(&out[1], tsd * sc);
    atomicAdd(&out[2], tss * sc);
    atomicAdd(&out[0], tss * sc);  // loss = 0*detail + 1*smooth
  }
}

// ---------------------------------------------------------------------------
// Write final reflectance / illumination (scalar stores; d_out+3 not 16B aligned).
__global__ __launch_bounds__(256) void final_k(const float* __restrict__ inp,
                                               const float* __restrict__ acc,
                                               float* __restrict__ refl,
                                               float* __restrict__ illum) {
  int idx = blockIdx.x * 256 + threadIdx.x;
  float R = acc[idx] * (1.f / 3.f);
  float li = logf(fmaxf(inp[idx], EPSV));
  refl[idx] = R;
  illum[idx] = li - R;
}

// ---------------------------------------------------------------------------
extern "C" void kernel_launch(void* const* d_in, const int* in_sizes, int n_in,
                              void* d_out, int out_size, void* d_ws, size_t ws_size,
                              hipStream_t stream) {
  const float* inp = (const float*)d_in[0];
  float* out = (float*)d_out;
  float* ws = (float*)d_ws;
  // ws layout (floats): taps[3*1536 pad to 8192] | W[1M] | Wt[1M] | T[6M] | acc[6M]
  float* taps = ws;
  float* W = ws + 8192;
  float* Wt = W + IMGSZ;
  float* T = Wt + IMGSZ;
  float* acc = T + (size_t)NIMG * IMGSZ;
  float* refl = out + 3;
  float* illum = refl + (size_t)NIMG * IMGSZ;

  hipMemsetAsync(out, 0, 3 * sizeof(float), stream);
  build_taps_k<<<3, 256, 0, stream>>>(taps);
  const int kss[3] = {91, 481, 1501};
  dim3 grid(IMN / BN, IMN / BM, NIMG);
  for (int s = 0; s < 3; s++) {
    build_w_k<<<IMN, 256, 0, stream>>>(taps + s * 1536, kss[s], W, Wt);
    gemm_blurV<<<grid, 256, 0, stream>>>(W, inp, T);
    gemm_blurH<<<grid, 256, 0, stream>>>(T, Wt, inp, acc, s == 0 ? 1 : 0);
  }
  int nb = NIMG * IMGSZ / 256;
  loss_k<<<nb, 256, 0, stream>>>(inp, acc, out);
  final_k<<<nb, 256, 0, stream>>>(inp, acc, refl, illum);
}

// Round 2
// 1316.867 us; speedup vs baseline: 1.7269x; 1.7269x over previous
//
#include <hip/hip_runtime.h>
#include <math.h>

#define IMN 1024
#define IMGSZ (IMN * IMN)
#define NIMG 6
#define EPSV 0.001f
#define BM 128
#define BN 128
#define BK 16
#define LDP 132  // padded LDS leading dim (16B-aligned rows, breaks 4-way conflicts)
#define NB1 4096 // stage-1 loss blocks (partials overlay the dead taps region: 2*4096 floats)

// ---------------------------------------------------------------------------
// Gaussian taps: k[i] = exp(-0.5*((i-(ks-1)/2)/sigma)^2), normalized.
// One block per sigma.
__global__ __launch_bounds__(256) void build_taps_k(float* __restrict__ taps) {
  const int kss[3] = {91, 481, 1501};
  const float sig[3] = {15.f, 80.f, 250.f};
  int s = blockIdx.x;
  int ks = kss[s];
  float sigma = sig[s];
  float* t = taps + s * 1536;
  float ctr = (float)(ks - 1) * 0.5f;
  __shared__ float red[256];
  float loc = 0.f;
  for (int i = threadIdx.x; i < ks; i += 256) {
    float x = ((float)i - ctr) / sigma;
    float v = expf(-0.5f * x * x);
    t[i] = v;
    loc += v;
  }
  red[threadIdx.x] = loc;
  __syncthreads();
  for (int o = 128; o > 0; o >>= 1) {
    if (threadIdx.x < o) red[threadIdx.x] += red[threadIdx.x + o];
    __syncthreads();
  }
  float inv = 1.f / red[0];
  for (int i = threadIdx.x; i < ks; i += 256) t[i] *= inv;
}

// ---------------------------------------------------------------------------
// Build blur operator W (and its transpose) for one sigma.
// W[r,j] = sum of taps t where reflect(r + t - p) == j. One block per row r.
__global__ __launch_bounds__(256) void build_w_k(const float* __restrict__ taps, int ks,
                                                 float* __restrict__ W,
                                                 float* __restrict__ Wt) {
  int r = blockIdx.x;
  int p = ks >> 1;
  __shared__ float row[IMN];
  for (int i = threadIdx.x; i < IMN; i += 256) row[i] = 0.f;
  __syncthreads();
  for (int t = threadIdx.x; t < ks; t += 256) {
    int q = r + t - p;
    int j = q < 0 ? -q : (q > IMN - 1 ? 2 * (IMN - 1) - q : q);
    atomicAdd(&row[j], taps[t]);  // LDS atomics, low contention
  }
  __syncthreads();
  for (int i = threadIdx.x; i < IMN; i += 256) {
    float v = row[i];
    W[r * IMN + i] = v;
    Wt[i * IMN + r] = v;
  }
}

// ---------------------------------------------------------------------------
// Pass 1 (vertical blur): T_z = W * clip(img_z).  NN GEMM 1024^3, batched z=0..5.
__global__ __launch_bounds__(256) void gemm_blurV(const float* __restrict__ W,
                                                  const float* __restrict__ inp,
                                                  float* __restrict__ T) {
  __shared__ float As[BK][LDP];
  __shared__ float Bs[BK][LDP];
  int z = blockIdx.z;
  const float* Bg = inp + z * IMGSZ;
  float* Cg = T + z * IMGSZ;
  int bm = blockIdx.y * BM;
  int bn = blockIdx.x * BN;
  int tid = threadIdx.x;
  int tx = tid & 15, ty = tid >> 4;
  float acc[2][2][4][4] = {};
  for (int k0 = 0; k0 < IMN; k0 += BK) {
    float4 av[2], bv[2];
#pragma unroll
    for (int i = 0; i < 2; i++) {
      int v = tid + i * 256;
      int arow = v >> 2, akq = (v & 3) * 4;
      av[i] = *(const float4*)&W[(bm + arow) * IMN + k0 + akq];
      int brow = v >> 5, bnq = (v & 31) * 4;
      bv[i] = *(const float4*)&Bg[(k0 + brow) * IMN + bn + bnq];
    }
    __syncthreads();
#pragma unroll
    for (int i = 0; i < 2; i++) {
      int v = tid + i * 256;
      int arow = v >> 2, akq = (v & 3) * 4;
      As[akq + 0][arow] = av[i].x;
      As[akq + 1][arow] = av[i].y;
      As[akq + 2][arow] = av[i].z;
      As[akq + 3][arow] = av[i].w;
      int brow = v >> 5, bnq = (v & 31) * 4;
      float4 cb;
      cb.x = fminf(fmaxf(bv[i].x, EPSV), 1.f);
      cb.y = fminf(fmaxf(bv[i].y, EPSV), 1.f);
      cb.z = fminf(fmaxf(bv[i].z, EPSV), 1.f);
      cb.w = fminf(fmaxf(bv[i].w, EPSV), 1.f);
      *(float4*)&Bs[brow][bnq] = cb;
    }
    __syncthreads();
#pragma unroll
    for (int kk = 0; kk < BK; kk++) {
      float a[2][4], b[2][4];
      *(float4*)a[0] = *(const float4*)&As[kk][ty * 4];
      *(float4*)a[1] = *(const float4*)&As[kk][ty * 4 + 64];
      *(float4*)b[0] = *(const float4*)&Bs[kk][tx * 4];
      *(float4*)b[1] = *(const float4*)&Bs[kk][tx * 4 + 64];
#pragma unroll
      for (int i = 0; i < 2; i++)
#pragma unroll
        for (int ri = 0; ri < 4; ri++)
#pragma unroll
          for (int j = 0; j < 2; j++)
#pragma unroll
            for (int ci = 0; ci < 4; ci++)
              acc[i][j][ri][ci] = fmaf(a[i][ri], b[j][ci], acc[i][j][ri][ci]);
    }
  }
#pragma unroll
  for (int i = 0; i < 2; i++)
#pragma unroll
    for (int ri = 0; ri < 4; ri++) {
      int row = bm + ty * 4 + i * 64 + ri;
#pragma unroll
      for (int j = 0; j < 2; j++) {
        float4 v = make_float4(acc[i][j][ri][0], acc[i][j][ri][1],
                               acc[i][j][ri][2], acc[i][j][ri][3]);
        *(float4*)&Cg[row * IMN + bn + tx * 4 + j * 64] = v;
      }
    }
}

// ---------------------------------------------------------------------------
// Pass 2 (horizontal blur): Blur_z = T_z * Wt; fused epilogue:
// acc_z += log(clip(img)) - log(max(blur, eps))   (write-fresh when first).
__global__ __launch_bounds__(256) void gemm_blurH(const float* __restrict__ T,
                                                  const float* __restrict__ Wt,
                                                  const float* __restrict__ inp,
                                                  float* __restrict__ accb, int first) {
  __shared__ float As[BK][LDP];
  __shared__ float Bs[BK][LDP];
  int z = blockIdx.z;
  const float* Ag = T + z * IMGSZ;
  int bm = blockIdx.y * BM;
  int bn = blockIdx.x * BN;
  int tid = threadIdx.x;
  int tx = tid & 15, ty = tid >> 4;
  float acc[2][2][4][4] = {};
  for (int k0 = 0; k0 < IMN; k0 += BK) {
    float4 av[2], bv[2];
#pragma unroll
    for (int i = 0; i < 2; i++) {
      int v = tid + i * 256;
      int arow = v >> 2, akq = (v & 3) * 4;
      av[i] = *(const float4*)&Ag[(bm + arow) * IMN + k0 + akq];
      int brow = v >> 5, bnq = (v & 31) * 4;
      bv[i] = *(const float4*)&Wt[(k0 + brow) * IMN + bn + bnq];
    }
    __syncthreads();
#pragma unroll
    for (int i = 0; i < 2; i++) {
      int v = tid + i * 256;
      int arow = v >> 2, akq = (v & 3) * 4;
      As[akq + 0][arow] = av[i].x;
      As[akq + 1][arow] = av[i].y;
      As[akq + 2][arow] = av[i].z;
      As[akq + 3][arow] = av[i].w;
      int brow = v >> 5, bnq = (v & 31) * 4;
      *(float4*)&Bs[brow][bnq] = bv[i];
    }
    __syncthreads();
#pragma unroll
    for (int kk = 0; kk < BK; kk++) {
      float a[2][4], b[2][4];
      *(float4*)a[0] = *(const float4*)&As[kk][ty * 4];
      *(float4*)a[1] = *(const float4*)&As[kk][ty * 4 + 64];
      *(float4*)b[0] = *(const float4*)&Bs[kk][tx * 4];
      *(float4*)b[1] = *(const float4*)&Bs[kk][tx * 4 + 64];
#pragma unroll
      for (int i = 0; i < 2; i++)
#pragma unroll
        for (int ri = 0; ri < 4; ri++)
#pragma unroll
          for (int j = 0; j < 2; j++)
#pragma unroll
            for (int ci = 0; ci < 4; ci++)
              acc[i][j][ri][ci] = fmaf(a[i][ri], b[j][ci], acc[i][j][ri][ci]);
    }
  }
#pragma unroll
  for (int i = 0; i < 2; i++)
#pragma unroll
    for (int ri = 0; ri < 4; ri++) {
      int row = bm + ty * 4 + i * 64 + ri;
#pragma unroll
      for (int j = 0; j < 2; j++) {
        int col = bn + tx * 4 + j * 64;
        int g = z * IMGSZ + row * IMN + col;
        float4 iv = *(const float4*)&inp[g];
        float4 r;
        r.x = logf(fminf(fmaxf(iv.x, EPSV), 1.f)) - logf(fmaxf(acc[i][j][ri][0], EPSV));
        r.y = logf(fminf(fmaxf(iv.y, EPSV), 1.f)) - logf(fmaxf(acc[i][j][ri][1], EPSV));
        r.z = logf(fminf(fmaxf(iv.z, EPSV), 1.f)) - logf(fmaxf(acc[i][j][ri][2], EPSV));
        r.w = logf(fminf(fmaxf(iv.w, EPSV), 1.f)) - logf(fmaxf(acc[i][j][ri][3], EPSV));
        if (!first) {
          float4 pa = *(const float4*)&accb[g];
          r.x += pa.x; r.y += pa.y; r.z += pa.z; r.w += pa.w;
        }
        *(float4*)&accb[g] = r;
      }
    }
}

// ---------------------------------------------------------------------------
// Fused loss stage 1 + final outputs. Grid-stride over all 6M elements:
//   R = acc/3; I = log(max(in,eps)) - R; store refl, illum;
//   accumulate |grad R| (detail) and |grad I| (smooth) into block partials.
// NO same-address atomics: per-block partials go to ws (pd/ps arrays).
__global__ __launch_bounds__(256) void loss_stage1_k(const float* __restrict__ inp,
                                                     const float* __restrict__ acc,
                                                     float* __restrict__ refl,
                                                     float* __restrict__ illum,
                                                     float* __restrict__ pd,
                                                     float* __restrict__ ps) {
  const int stride = NB1 * 256;
  float sd = 0.f, ss = 0.f;
  for (int i = blockIdx.x * 256 + threadIdx.x; i < NIMG * IMGSZ; i += stride) {
    int c = i & (IMN - 1);
    int rr = (i >> 10) & (IMN - 1);
    float R0 = acc[i] * (1.f / 3.f);
    float I0 = logf(fmaxf(inp[i], EPSV)) - R0;
    refl[i] = R0;
    illum[i] = I0;
    if (c < IMN - 1) {
      float R1 = acc[i + 1] * (1.f / 3.f);
      float I1 = logf(fmaxf(inp[i + 1], EPSV)) - R1;
      sd += fabsf(R0 - R1);
      ss += fabsf(I0 - I1);
    }
    if (rr < IMN - 1) {
      float R2 = acc[i + IMN] * (1.f / 3.f);
      float I2 = logf(fmaxf(inp[i + IMN], EPSV)) - R2;
      sd += fabsf(R0 - R2);
      ss += fabsf(I0 - I2);
    }
  }
  for (int o = 32; o > 0; o >>= 1) {
    sd += __shfl_down(sd, o);
    ss += __shfl_down(ss, o);
  }
  __shared__ float rsd[4], rss[4];
  int lane = threadIdx.x & 63, w = threadIdx.x >> 6;
  if (lane == 0) { rsd[w] = sd; rss[w] = ss; }
  __syncthreads();
  if (threadIdx.x == 0) {
    pd[blockIdx.x] = rsd[0] + rsd[1] + rsd[2] + rsd[3];
    ps[blockIdx.x] = rss[0] + rss[1] + rss[2] + rss[3];
  }
}

// ---------------------------------------------------------------------------
// Stage 2: single block reduces NB1 partials, writes the three scalars.
__global__ __launch_bounds__(256) void loss_stage2_k(const float* __restrict__ pd,
                                                     const float* __restrict__ ps,
                                                     float* __restrict__ out) {
  float sd = 0.f, ss = 0.f;
  for (int i = threadIdx.x; i < NB1; i += 256) {
    sd += pd[i];
    ss += ps[i];
  }
  for (int o = 32; o > 0; o >>= 1) {
    sd += __shfl_down(sd, o);
    ss += __shfl_down(ss, o);
  }
  __shared__ float rsd[4], rss[4];
  int lane = threadIdx.x & 63, w = threadIdx.x >> 6;
  if (lane == 0) { rsd[w] = sd; rss[w] = ss; }
  __syncthreads();
  if (threadIdx.x == 0) {
    float tsd = rsd[0] + rsd[1] + rsd[2] + rsd[3];
    float tss = rss[0] + rss[1] + rss[2] + rss[3];
    const float sc = 1.f / 6285312.f;  // 2*3*1024*1023 (count for gx == count for gy)
    out[0] = tss * sc;  // loss = 0*detail + 1*smooth
    out[1] = tsd * sc;  // loss_detail
    out[2] = tss * sc;  // loss_smooth_illum
  }
}

// ---------------------------------------------------------------------------
extern "C" void kernel_launch(void* const* d_in, const int* in_sizes, int n_in,
                              void* d_out, int out_size, void* d_ws, size_t ws_size,
                              hipStream_t stream) {
  const float* inp = (const float*)d_in[0];
  float* out = (float*)d_out;
  float* ws = (float*)d_ws;
  // ws layout (floats): taps[8192] | W[1M] | Wt[1M] | T[6M] | acc[6M]
  // partials pd/ps (2*4096 floats) OVERLAY the taps region — taps are dead
  // by the time loss_stage1 runs, so ws footprint is unchanged vs round 1.
  float* taps = ws;
  float* W = ws + 8192;
  float* Wt = W + IMGSZ;
  float* T = Wt + IMGSZ;
  float* acc = T + (size_t)NIMG * IMGSZ;
  float* pd = ws;          // 4096 floats
  float* ps = ws + NB1;    // 4096 floats
  float* refl = out + 3;
  float* illum = refl + (size_t)NIMG * IMGSZ;

  build_taps_k<<<3, 256, 0, stream>>>(taps);
  const int kss[3] = {91, 481, 1501};
  dim3 grid(IMN / BN, IMN / BM, NIMG);
  for (int s = 0; s < 3; s++) {
    build_w_k<<<IMN, 256, 0, stream>>>(taps + s * 1536, kss[s], W, Wt);
    gemm_blurV<<<grid, 256, 0, stream>>>(W, inp, T);
    gemm_blurH<<<grid, 256, 0, stream>>>(T, Wt, inp, acc, s == 0 ? 1 : 0);
  }
  loss_stage1_k<<<NB1, 256, 0, stream>>>(inp, acc, refl, illum, pd, ps);
  loss_stage2_k<<<1, 256, 0, stream>>>(pd, ps, out);
}

// Round 3
// 771.150 us; speedup vs baseline: 2.9489x; 1.7077x over previous
//
#include <hip/hip_runtime.h>
#include <math.h>

#define IMN 1024
#define IMGSZ (IMN * IMN)
#define NIMG 6
#define EPSV 0.001f
#define LDK 40   // LDS row stride in bf16 elems (padded: conflict-free b128 frag reads)
#define NB1 4096 // stage-1 loss blocks

typedef unsigned short u16;
typedef __attribute__((ext_vector_type(8))) short short8;     // 8 bf16 = 4 VGPRs
typedef __attribute__((ext_vector_type(16))) float floatx16;  // 32x32 C/D = 16 f32

// ---------------------------------------------------------------------------
__global__ __launch_bounds__(256) void build_taps_k(float* __restrict__ taps) {
  const int kss[3] = {91, 481, 1501};
  const float sig[3] = {15.f, 80.f, 250.f};
  int s = blockIdx.x;
  int ks = kss[s];
  float sigma = sig[s];
  float* t = taps + s * 1536;
  float ctr = (float)(ks - 1) * 0.5f;
  __shared__ float red[256];
  float loc = 0.f;
  for (int i = threadIdx.x; i < ks; i += 256) {
    float x = ((float)i - ctr) / sigma;
    float v = expf(-0.5f * x * x);
    t[i] = v;
    loc += v;
  }
  red[threadIdx.x] = loc;
  __syncthreads();
  for (int o = 128; o > 0; o >>= 1) {
    if (threadIdx.x < o) red[threadIdx.x] += red[threadIdx.x + o];
    __syncthreads();
  }
  float inv = 1.f / red[0];
  for (int i = threadIdx.x; i < ks; i += 256) t[i] *= inv;
}

// ---------------------------------------------------------------------------
// W[r,j] = sum of taps t where reflect(r + t - p) == j. One block per row r.
__global__ __launch_bounds__(256) void build_w_k(const float* __restrict__ taps, int ks,
                                                 float* __restrict__ W) {
  int r = blockIdx.x;
  int p = ks >> 1;
  __shared__ float row[IMN];
  for (int i = threadIdx.x; i < IMN; i += 256) row[i] = 0.f;
  __syncthreads();
  for (int t = threadIdx.x; t < ks; t += 256) {
    int q = r + t - p;
    int j = q < 0 ? -q : (q > IMN - 1 ? 2 * (IMN - 1) - q : q);
    atomicAdd(&row[j], taps[t]);
  }
  __syncthreads();
  for (int i = threadIdx.x; i < IMN; i += 256) W[r * IMN + i] = row[i];
}

// ---------------------------------------------------------------------------
// Stage a 128x32 fp32 tile into LDS as bf16 hi/lo (truncation split + RNE lo).
// All source values are >= 0 here, so truncation keeps lo >= 0.
__device__ __forceinline__ unsigned pk(u16 a, u16 b) {
  return (unsigned)a | ((unsigned)b << 16);
}

__device__ __forceinline__ void stage(const float* __restrict__ src, int row0, int k0,
                                      u16* __restrict__ hi, u16* __restrict__ lo,
                                      int tid, bool doclip) {
  int tr = tid >> 1;
  int tc = (tid & 1) << 4;
  const float* p = src + (size_t)(row0 + tr) * IMN + k0 + tc;
  float x[16];
  *(float4*)&x[0] = *(const float4*)&p[0];
  *(float4*)&x[4] = *(const float4*)&p[4];
  *(float4*)&x[8] = *(const float4*)&p[8];
  *(float4*)&x[12] = *(const float4*)&p[12];
  u16 hb[16], lb[16];
#pragma unroll
  for (int e = 0; e < 16; e++) {
    float v = x[e];
    if (doclip) v = fminf(fmaxf(v, EPSV), 1.f);
    unsigned u = __float_as_uint(v);
    hb[e] = (u16)(u >> 16);
    float lof = v - __uint_as_float(u & 0xFFFF0000u);
    unsigned lu = __float_as_uint(lof);
    lu = lu + 0x7FFFu + ((lu >> 16) & 1u);  // RNE to bf16
    lb[e] = (u16)(lu >> 16);
  }
  u16* hd = hi + tr * LDK + tc;
  u16* ld = lo + tr * LDK + tc;
  uint4 h0 = make_uint4(pk(hb[0], hb[1]), pk(hb[2], hb[3]), pk(hb[4], hb[5]), pk(hb[6], hb[7]));
  uint4 h1 = make_uint4(pk(hb[8], hb[9]), pk(hb[10], hb[11]), pk(hb[12], hb[13]), pk(hb[14], hb[15]));
  uint4 l0 = make_uint4(pk(lb[0], lb[1]), pk(lb[2], lb[3]), pk(lb[4], lb[5]), pk(lb[6], lb[7]));
  uint4 l1 = make_uint4(pk(lb[8], lb[9]), pk(lb[10], lb[11]), pk(lb[12], lb[13]), pk(lb[14], lb[15]));
  *(uint4*)&hd[0] = h0;
  *(uint4*)&hd[8] = h1;
  *(uint4*)&ld[0] = l0;
  *(uint4*)&ld[8] = l1;
}

// ---------------------------------------------------------------------------
// bf16x3 MFMA GEMM, 128x128 tile, K=1024, 32x32x16 MFMA, wave tile 64x64.
// z slice: s = z/6 selects W, i = z%6 selects image.
// EPI=0 (pass 1, horizontal blur): A = img[i] (clipped), C -> Ut[z] TRANSPOSED.
// EPI=1 (pass 2, vertical blur):   A = Ut[z],           C -> atomicAdd(log) into acc[i].
// Both passes: B-fragment [n][k] = rows of W (no transpose ever needed).
template <int EPI>
__global__ __launch_bounds__(256) void gemm_pass(const float* __restrict__ Abase,
                                                 const float* __restrict__ Wbase,
                                                 float* __restrict__ Obase) {
  __shared__ u16 Ah[128 * LDK], Al[128 * LDK], Bh[128 * LDK], Bl[128 * LDK];
  int z = blockIdx.z;
  int s = z / 6;
  int i = z - s * 6;
  const float* Ag = Abase + (size_t)(EPI == 0 ? i : z) * IMGSZ;
  const float* Wg = Wbase + (size_t)s * IMGSZ;
  float* Og = Obase + (size_t)(EPI == 0 ? z : i) * IMGSZ;
  int bm = blockIdx.y * 128, bn = blockIdx.x * 128;
  int tid = threadIdx.x;
  int lane = tid & 63, w = tid >> 6;
  int wm = (w >> 1) * 64, wn = (w & 1) * 64;
  int lrow = lane & 31, lh = lane >> 5;
  floatx16 acc[2][2] = {};

  for (int k0 = 0; k0 < IMN; k0 += 32) {
    stage(Ag, bm, k0, Ah, Al, tid, EPI == 0);
    stage(Wg, bn, k0, Bh, Bl, tid, false);
    __syncthreads();
#pragma unroll
    for (int kk = 0; kk < 32; kk += 16) {
      short8 ah[2], al[2], bh[2], bl[2];
#pragma unroll
      for (int mt = 0; mt < 2; mt++) {
        int off = (wm + mt * 32 + lrow) * LDK + kk + lh * 8;
        ah[mt] = *(const short8*)&Ah[off];
        al[mt] = *(const short8*)&Al[off];
      }
#pragma unroll
      for (int nt = 0; nt < 2; nt++) {
        int off = (wn + nt * 32 + lrow) * LDK + kk + lh * 8;
        bh[nt] = *(const short8*)&Bh[off];
        bl[nt] = *(const short8*)&Bl[off];
      }
#pragma unroll
      for (int mt = 0; mt < 2; mt++)
#pragma unroll
        for (int nt = 0; nt < 2; nt++) {
          acc[mt][nt] = __builtin_amdgcn_mfma_f32_32x32x16_bf16(ah[mt], bh[nt], acc[mt][nt], 0, 0, 0);
          acc[mt][nt] = __builtin_amdgcn_mfma_f32_32x32x16_bf16(ah[mt], bl[nt], acc[mt][nt], 0, 0, 0);
          acc[mt][nt] = __builtin_amdgcn_mfma_f32_32x32x16_bf16(al[mt], bh[nt], acc[mt][nt], 0, 0, 0);
        }
    }
    __syncthreads();
  }

  // Epilogue. C/D layout (verified): col = lane&31, row = (reg&3)+8*(reg>>2)+4*(lane>>5).
  // M-dim = A rows, N-dim = W rows. Both passes write Og[ncoord*IMN + mcoord].
#pragma unroll
  for (int mt = 0; mt < 2; mt++)
#pragma unroll
    for (int nt = 0; nt < 2; nt++) {
      int nc = bn + wn + nt * 32 + lrow;
#pragma unroll
      for (int rq = 0; rq < 4; rq++) {
        int mc = bm + wm + mt * 32 + rq * 8 + lh * 4;
        if (EPI == 0) {
          float4 v = make_float4(acc[mt][nt][rq * 4 + 0], acc[mt][nt][rq * 4 + 1],
                                 acc[mt][nt][rq * 4 + 2], acc[mt][nt][rq * 4 + 3]);
          *(float4*)&Og[(size_t)nc * IMN + mc] = v;  // Ut[n][m] (transposed store)
        } else {
#pragma unroll
          for (int e = 0; e < 4; e++) {
            float bv = logf(fmaxf(acc[mt][nt][rq * 4 + e], EPSV));
            atomicAdd(&Og[(size_t)nc * IMN + mc + e], bv);  // acc[j][n] += log blur_s
          }
        }
      }
    }
}

// ---------------------------------------------------------------------------
// acc = sum_s log(max(blur_s, eps));  R = log(clip(img)) - acc/3;  I = acc/3.
__global__ __launch_bounds__(256) void loss_stage1_k(const float* __restrict__ inp,
                                                     const float* __restrict__ acc,
                                                     float* __restrict__ refl,
                                                     float* __restrict__ illum,
                                                     float* __restrict__ pd,
                                                     float* __restrict__ ps) {
  const int stride = NB1 * 256;
  float sd = 0.f, ss = 0.f;
  for (int i = blockIdx.x * 256 + threadIdx.x; i < NIMG * IMGSZ; i += stride) {
    int c = i & (IMN - 1);
    int rr = (i >> 10) & (IMN - 1);
    float I0 = acc[i] * (1.f / 3.f);
    float R0 = logf(fmaxf(inp[i], EPSV)) - I0;
    refl[i] = R0;
    illum[i] = I0;
    if (c < IMN - 1) {
      float I1 = acc[i + 1] * (1.f / 3.f);
      float R1 = logf(fmaxf(inp[i + 1], EPSV)) - I1;
      sd += fabsf(R0 - R1);
      ss += fabsf(I0 - I1);
    }
    if (rr < IMN - 1) {
      float I2 = acc[i + IMN] * (1.f / 3.f);
      float R2 = logf(fmaxf(inp[i + IMN], EPSV)) - I2;
      sd += fabsf(R0 - R2);
      ss += fabsf(I0 - I2);
    }
  }
  for (int o = 32; o > 0; o >>= 1) {
    sd += __shfl_down(sd, o);
    ss += __shfl_down(ss, o);
  }
  __shared__ float rsd[4], rss[4];
  int lane = threadIdx.x & 63, w = threadIdx.x >> 6;
  if (lane == 0) { rsd[w] = sd; rss[w] = ss; }
  __syncthreads();
  if (threadIdx.x == 0) {
    pd[blockIdx.x] = rsd[0] + rsd[1] + rsd[2] + rsd[3];
    ps[blockIdx.x] = rss[0] + rss[1] + rss[2] + rss[3];
  }
}

__global__ __launch_bounds__(256) void loss_stage2_k(const float* __restrict__ pd,
                                                     const float* __restrict__ ps,
                                                     float* __restrict__ out) {
  float sd = 0.f, ss = 0.f;
  for (int i = threadIdx.x; i < NB1; i += 256) {
    sd += pd[i];
    ss += ps[i];
  }
  for (int o = 32; o > 0; o >>= 1) {
    sd += __shfl_down(sd, o);
    ss += __shfl_down(ss, o);
  }
  __shared__ float rsd[4], rss[4];
  int lane = threadIdx.x & 63, w = threadIdx.x >> 6;
  if (lane == 0) { rsd[w] = sd; rss[w] = ss; }
  __syncthreads();
  if (threadIdx.x == 0) {
    float tsd = rsd[0] + rsd[1] + rsd[2] + rsd[3];
    float tss = rss[0] + rss[1] + rss[2] + rss[3];
    const float sc = 1.f / 6285312.f;  // 2*3*1024*1023
    out[0] = tss * sc;
    out[1] = tsd * sc;
    out[2] = tss * sc;
  }
}

// ---------------------------------------------------------------------------
extern "C" void kernel_launch(void* const* d_in, const int* in_sizes, int n_in,
                              void* d_out, int out_size, void* d_ws, size_t ws_size,
                              hipStream_t stream) {
  const float* inp = (const float*)d_in[0];
  float* out = (float*)d_out;
  float* ws = (float*)d_ws;
  float* refl = out + 3;
  float* illum = refl + (size_t)NIMG * IMGSZ;
  const int kss[3] = {91, 481, 1501};

  // Mode A (all 3 sigmas in one dispatch, z=18): taps|W*3|Ut*18|acc*6 = ~113 MB.
  // Mode B (per-sigma loop, z=6):                taps|W*1|Ut*6 |acc*6 = ~55 MB.
  const size_t needA = (size_t)(8192 + 27 * IMGSZ) * sizeof(float);
  bool modeA = ws_size >= needA;

  float* taps = ws;
  float* pd = ws;        // overlays taps (dead by loss time)
  float* ps = ws + NB1;
  float* W = ws + 8192;
  int nw = modeA ? 3 : 1;
  float* Ut = W + (size_t)nw * IMGSZ;
  int nz = modeA ? 18 : 6;
  float* acc = Ut + (size_t)nz * IMGSZ;

  build_taps_k<<<3, 256, 0, stream>>>(taps);
  hipMemsetAsync(acc, 0, (size_t)NIMG * IMGSZ * sizeof(float), stream);

  dim3 grid(8, 8, nz);
  if (modeA) {
    for (int s = 0; s < 3; s++)
      build_w_k<<<IMN, 256, 0, stream>>>(taps + s * 1536, kss[s], W + (size_t)s * IMGSZ);
    gemm_pass<0><<<grid, 256, 0, stream>>>(inp, W, Ut);
    gemm_pass<1><<<grid, 256, 0, stream>>>(Ut, W, acc);
  } else {
    for (int s = 0; s < 3; s++) {
      build_w_k<<<IMN, 256, 0, stream>>>(taps + s * 1536, kss[s], W);
      gemm_pass<0><<<grid, 256, 0, stream>>>(inp, W, Ut);
      gemm_pass<1><<<grid, 256, 0, stream>>>(Ut, W, acc);
    }
  }
  loss_stage1_k<<<NB1, 256, 0, stream>>>(inp, acc, refl, illum, pd, ps);
  loss_stage2_k<<<1, 256, 0, stream>>>(pd, ps, out);
}

// Round 5
// 411.938 us; speedup vs baseline: 5.5204x; 1.8720x over previous
//
#include <hip/hip_runtime.h>
#include <math.h>

#define IMN 1024
#define IMGSZ (IMN * IMN)
#define NIMG 6
#define EPSV 0.001f
#define LDK 40   // staging LDS row stride (u16 elems): 80 B, 16B-aligned
#define NB1 4096

typedef unsigned short u16;
typedef __attribute__((ext_vector_type(8))) short short8;     // 8 bf16 = 4 VGPRs
typedef __attribute__((ext_vector_type(16))) float floatx16;  // 32x32 C/D

// fp32 -> bf16 hi (truncate) + lo (RNE of residual). v >= 0 everywhere here.
__device__ __forceinline__ void split_bf16(float v, u16& h, u16& l) {
  unsigned u = __float_as_uint(v);
  h = (u16)(u >> 16);
  float lof = v - __uint_as_float(u & 0xFFFF0000u);
  unsigned lu = __float_as_uint(lof);
  lu = lu + 0x7FFFu + ((lu >> 16) & 1u);
  l = (u16)(lu >> 16);
}

// ---------------------------------------------------------------------------
__global__ __launch_bounds__(256) void build_taps_k(float* __restrict__ taps) {
  const int kss[3] = {91, 481, 1501};
  const float sig[3] = {15.f, 80.f, 250.f};
  int s = blockIdx.x;
  int ks = kss[s];
  float sigma = sig[s];
  float* t = taps + s * 1536;
  float ctr = (float)(ks - 1) * 0.5f;
  __shared__ float red[256];
  float loc = 0.f;
  for (int i = threadIdx.x; i < ks; i += 256) {
    float x = ((float)i - ctr) / sigma;
    float v = expf(-0.5f * x * x);
    t[i] = v;
    loc += v;
  }
  red[threadIdx.x] = loc;
  __syncthreads();
  for (int o = 128; o > 0; o >>= 1) {
    if (threadIdx.x < o) red[threadIdx.x] += red[threadIdx.x + o];
    __syncthreads();
  }
  float inv = 1.f / red[0];
  for (int i = threadIdx.x; i < ks; i += 256) t[i] *= inv;
}

// ---------------------------------------------------------------------------
// W[r,j] = sum of taps t with reflect(r+t-p)==j, written directly as bf16 hi/lo.
__global__ __launch_bounds__(256) void build_w_k(const float* __restrict__ taps, int ks,
                                                 u16* __restrict__ WHr, u16* __restrict__ WLr) {
  int r = blockIdx.x;
  int p = ks >> 1;
  __shared__ float row[IMN];
  for (int i = threadIdx.x; i < IMN; i += 256) row[i] = 0.f;
  __syncthreads();
  for (int t = threadIdx.x; t < ks; t += 256) {
    int q = r + t - p;
    int j = q < 0 ? -q : (q > IMN - 1 ? 2 * (IMN - 1) - q : q);
    atomicAdd(&row[j], taps[t]);
  }
  __syncthreads();
  for (int i = threadIdx.x; i < IMN; i += 256) {
    u16 h, l;
    split_bf16(row[i], h, l);
    WHr[r * IMN + i] = h;
    WLr[r * IMN + i] = l;
  }
}

// ---------------------------------------------------------------------------
// clip(img) -> bf16 hi/lo planes, once (removes 8x-replicated in-loop conversion).
__global__ __launch_bounds__(256) void split_img_k(const float* __restrict__ inp,
                                                   u16* __restrict__ H, u16* __restrict__ L) {
  int i4 = (blockIdx.x * 256 + threadIdx.x) * 4;
  float4 v = *(const float4*)&inp[i4];
  float x[4] = {v.x, v.y, v.z, v.w};
  u16 h[4], l[4];
#pragma unroll
  for (int e = 0; e < 4; e++) {
    float c = fminf(fmaxf(x[e], EPSV), 1.f);
    split_bf16(c, h[e], l[e]);
  }
  uint2 hp = make_uint2((unsigned)h[0] | ((unsigned)h[1] << 16),
                        (unsigned)h[2] | ((unsigned)h[3] << 16));
  uint2 lp = make_uint2((unsigned)l[0] | ((unsigned)l[1] << 16),
                        (unsigned)l[2] | ((unsigned)l[3] << 16));
  *(uint2*)&H[i4] = hp;
  *(uint2*)&L[i4] = lp;
}

// ---------------------------------------------------------------------------
// bf16x3 MFMA GEMM, 128x128 tile, 32x32x16, wave tile 64x64, K=1024.
// z: s = sBase + z/6 (W slice), i = z%6.
// EPI=0: A = imgH/L[i];  out = UtH/UtL[z]  (transposed, bf16 hi/lo, coalesced rows).
// EPI=1: A = UtH/L[z];   out = OF[outByZ? z : i] = log(max(blur,eps)), fp32
//        (rmw=1: += previous, per-sigma accumulation — no atomics, no races).
template <int EPI>
__global__ __launch_bounds__(256, 4) void gemm_pass(
    const u16* __restrict__ AH, const u16* __restrict__ AL,
    const u16* __restrict__ WH, const u16* __restrict__ WL,
    u16* __restrict__ OH, u16* __restrict__ OL, float* __restrict__ OF,
    int sBase, int outByZ, int rmw) {
  __shared__ u16 smem[4 * 128 * LDK];  // 40960 B
  u16* Ah = smem;
  u16* Al = smem + 128 * LDK;
  u16* Bh = smem + 2 * 128 * LDK;
  u16* Bl = smem + 3 * 128 * LDK;
  int z = blockIdx.z;
  int s = sBase + z / 6;
  int i = z - (z / 6) * 6;
  const u16* AgH = AH + (size_t)(EPI == 0 ? i : z) * IMGSZ;
  const u16* AgL = AL + (size_t)(EPI == 0 ? i : z) * IMGSZ;
  const u16* BgH = WH + (size_t)s * IMGSZ;
  const u16* BgL = WL + (size_t)s * IMGSZ;
  int bm = blockIdx.y * 128, bn = blockIdx.x * 128;
  int tid = threadIdx.x;
  int lane = tid & 63, w = tid >> 6;
  int wm = (w >> 1) * 64, wn = (w & 1) * 64;
  int lrow = lane & 31, lh = lane >> 5;
  int tr = tid >> 2, tc = (tid & 3) * 8;  // staging: 4 threads/row, 16B each
  floatx16 acc[2][2] = {};

  for (int k0 = 0; k0 < IMN; k0 += 32) {
    // pure bf16 16B copies (no conversion in the hot loop)
    uint4 a0h = *(const uint4*)&AgH[(size_t)(bm + tr) * IMN + k0 + tc];
    uint4 a1h = *(const uint4*)&AgH[(size_t)(bm + tr + 64) * IMN + k0 + tc];
    uint4 a0l = *(const uint4*)&AgL[(size_t)(bm + tr) * IMN + k0 + tc];
    uint4 a1l = *(const uint4*)&AgL[(size_t)(bm + tr + 64) * IMN + k0 + tc];
    uint4 b0h = *(const uint4*)&BgH[(size_t)(bn + tr) * IMN + k0 + tc];
    uint4 b1h = *(const uint4*)&BgH[(size_t)(bn + tr + 64) * IMN + k0 + tc];
    uint4 b0l = *(const uint4*)&BgL[(size_t)(bn + tr) * IMN + k0 + tc];
    uint4 b1l = *(const uint4*)&BgL[(size_t)(bn + tr + 64) * IMN + k0 + tc];
    *(uint4*)&Ah[tr * LDK + tc] = a0h;
    *(uint4*)&Ah[(tr + 64) * LDK + tc] = a1h;
    *(uint4*)&Al[tr * LDK + tc] = a0l;
    *(uint4*)&Al[(tr + 64) * LDK + tc] = a1l;
    *(uint4*)&Bh[tr * LDK + tc] = b0h;
    *(uint4*)&Bh[(tr + 64) * LDK + tc] = b1h;
    *(uint4*)&Bl[tr * LDK + tc] = b0l;
    *(uint4*)&Bl[(tr + 64) * LDK + tc] = b1l;
    __syncthreads();
#pragma unroll
    for (int kk = 0; kk < 32; kk += 16) {
      short8 ah[2], al[2], bh[2], bl[2];
#pragma unroll
      for (int mt = 0; mt < 2; mt++) {
        int off = (wm + mt * 32 + lrow) * LDK + kk + lh * 8;
        ah[mt] = *(const short8*)&Ah[off];
        al[mt] = *(const short8*)&Al[off];
      }
#pragma unroll
      for (int nt = 0; nt < 2; nt++) {
        int off = (wn + nt * 32 + lrow) * LDK + kk + lh * 8;
        bh[nt] = *(const short8*)&Bh[off];
        bl[nt] = *(const short8*)&Bl[off];
      }
#pragma unroll
      for (int mt = 0; mt < 2; mt++)
#pragma unroll
        for (int nt = 0; nt < 2; nt++) {
          acc[mt][nt] = __builtin_amdgcn_mfma_f32_32x32x16_bf16(ah[mt], bh[nt], acc[mt][nt], 0, 0, 0);
          acc[mt][nt] = __builtin_amdgcn_mfma_f32_32x32x16_bf16(ah[mt], bl[nt], acc[mt][nt], 0, 0, 0);
          acc[mt][nt] = __builtin_amdgcn_mfma_f32_32x32x16_bf16(al[mt], bh[nt], acc[mt][nt], 0, 0, 0);
        }
    }
    __syncthreads();
  }

  // Epilogue: per-wave 32x32 LDS transpose (stride 33: conflict-free), then
  // coalesced full-line row stores. C/D layout: col(n)=lane&31,
  // row(m)=(reg&3)+8*(reg>>2)+4*(lane>>5)  [verified end-to-end in round 3].
  float* lf = (float*)smem + w * 1056;  // 4 waves x 4224 B = 16896 <= 40960
#pragma unroll
  for (int mt = 0; mt < 2; mt++)
#pragma unroll
    for (int nt = 0; nt < 2; nt++) {
#pragma unroll
      for (int rq = 0; rq < 4; rq++)
#pragma unroll
        for (int e = 0; e < 4; e++)
          lf[lrow * 33 + rq * 8 + lh * 4 + e] = acc[mt][nt][rq * 4 + e];
      __syncthreads();
#pragma unroll
      for (int p = 0; p < 4; p++) {
        int rl = p * 8 + (lane >> 3);
        int cl = (lane & 7) * 4;
        float v0 = lf[rl * 33 + cl + 0];
        float v1 = lf[rl * 33 + cl + 1];
        float v2 = lf[rl * 33 + cl + 2];
        float v3 = lf[rl * 33 + cl + 3];
        int gn = bn + wn + nt * 32 + rl;  // output row
        int gm = bm + wm + mt * 32 + cl;  // output col (contiguous per 8 lanes)
        if (EPI == 0) {
          // FIX (round 4 bug): plane offset z*IMGSZ was missing here — all z
          // slices raced into plane 0 and pass 2 read poisoned memory.
          size_t go = (size_t)z * IMGSZ + (size_t)gn * IMN + gm;
          u16 h0, h1, h2, h3, l0, l1, l2, l3;
          split_bf16(v0, h0, l0);
          split_bf16(v1, h1, l1);
          split_bf16(v2, h2, l2);
          split_bf16(v3, h3, l3);
          uint2 hp = make_uint2((unsigned)h0 | ((unsigned)h1 << 16),
                                (unsigned)h2 | ((unsigned)h3 << 16));
          uint2 lp = make_uint2((unsigned)l0 | ((unsigned)l1 << 16),
                                (unsigned)l2 | ((unsigned)l3 << 16));
          *(uint2*)&OH[go] = hp;
          *(uint2*)&OL[go] = lp;
        } else {
          size_t go = (size_t)(outByZ ? z : i) * IMGSZ + (size_t)gn * IMN + gm;
          float4 r = make_float4(logf(fmaxf(v0, EPSV)), logf(fmaxf(v1, EPSV)),
                                 logf(fmaxf(v2, EPSV)), logf(fmaxf(v3, EPSV)));
          if (rmw) {
            float4 pa = *(const float4*)&OF[go];
            r.x += pa.x; r.y += pa.y; r.z += pa.z; r.w += pa.w;
          }
          *(float4*)&OF[go] = r;
        }
      }
      __syncthreads();
    }
}

// ---------------------------------------------------------------------------
// sumlog(i) = lb[i] (+ lb[i+6M] + lb[i+12M] if three); I = sumlog/3;
// R = log(max(in,eps)) - I. Partials to pd/ps (no same-address atomics).
__global__ __launch_bounds__(256) void loss_stage1_k(const float* __restrict__ inp,
                                                     const float* __restrict__ lb, int three,
                                                     float* __restrict__ refl,
                                                     float* __restrict__ illum,
                                                     float* __restrict__ pd,
                                                     float* __restrict__ ps) {
  const int stride = NB1 * 256;
  const int S = NIMG * IMGSZ;
  float sd = 0.f, ss = 0.f;
  for (int i = blockIdx.x * 256 + threadIdx.x; i < S; i += stride) {
    int c = i & (IMN - 1);
    int rr = (i >> 10) & (IMN - 1);
    float a0 = lb[i];
    if (three) a0 += lb[i + S] + lb[i + 2 * S];
    float I0 = a0 * (1.f / 3.f);
    float R0 = logf(fmaxf(inp[i], EPSV)) - I0;
    refl[i] = R0;
    illum[i] = I0;
    if (c < IMN - 1) {
      float a1 = lb[i + 1];
      if (three) a1 += lb[i + 1 + S] + lb[i + 1 + 2 * S];
      float I1 = a1 * (1.f / 3.f);
      float R1 = logf(fmaxf(inp[i + 1], EPSV)) - I1;
      sd += fabsf(R0 - R1);
      ss += fabsf(I0 - I1);
    }
    if (rr < IMN - 1) {
      float a2 = lb[i + IMN];
      if (three) a2 += lb[i + IMN + S] + lb[i + IMN + 2 * S];
      float I2 = a2 * (1.f / 3.f);
      float R2 = logf(fmaxf(inp[i + IMN], EPSV)) - I2;
      sd += fabsf(R0 - R2);
      ss += fabsf(I0 - I2);
    }
  }
  for (int o = 32; o > 0; o >>= 1) {
    sd += __shfl_down(sd, o);
    ss += __shfl_down(ss, o);
  }
  __shared__ float rsd[4], rss[4];
  int lane = threadIdx.x & 63, w = threadIdx.x >> 6;
  if (lane == 0) { rsd[w] = sd; rss[w] = ss; }
  __syncthreads();
  if (threadIdx.x == 0) {
    pd[blockIdx.x] = rsd[0] + rsd[1] + rsd[2] + rsd[3];
    ps[blockIdx.x] = rss[0] + rss[1] + rss[2] + rss[3];
  }
}

__global__ __launch_bounds__(256) void loss_stage2_k(const float* __restrict__ pd,
                                                     const float* __restrict__ ps,
                                                     float* __restrict__ out) {
  float sd = 0.f, ss = 0.f;
  for (int i = threadIdx.x; i < NB1; i += 256) {
    sd += pd[i];
    ss += ps[i];
  }
  for (int o = 32; o > 0; o >>= 1) {
    sd += __shfl_down(sd, o);
    ss += __shfl_down(ss, o);
  }
  __shared__ float rsd[4], rss[4];
  int lane = threadIdx.x & 63, w = threadIdx.x >> 6;
  if (lane == 0) { rsd[w] = sd; rss[w] = ss; }
  __syncthreads();
  if (threadIdx.x == 0) {
    float tsd = rsd[0] + rsd[1] + rsd[2] + rsd[3];
    float tss = rss[0] + rss[1] + rss[2] + rss[3];
    const float sc = 1.f / 6285312.f;  // 2*3*1024*1023
    out[0] = tss * sc;
    out[1] = tsd * sc;
    out[2] = tss * sc;
  }
}

// ---------------------------------------------------------------------------
extern "C" void kernel_launch(void* const* d_in, const int* in_sizes, int n_in,
                              void* d_out, int out_size, void* d_ws, size_t ws_size,
                              hipStream_t stream) {
  const float* inp = (const float*)d_in[0];
  float* out = (float*)d_out;
  float* refl = out + 3;
  float* illum = refl + (size_t)NIMG * IMGSZ;
  const int kss[3] = {91, 481, 1501};

  char* p = (char*)d_ws;
  float* taps = (float*)p;                  p += 32768;
  u16* WH = (u16*)p;                        p += (size_t)3 * IMGSZ * 2;
  u16* WL = (u16*)p;                        p += (size_t)3 * IMGSZ * 2;
  u16* imgH = (u16*)p;                      p += (size_t)NIMG * IMGSZ * 2;
  u16* imgL = (u16*)p;                      p += (size_t)NIMG * IMGSZ * 2;
  size_t fixed = (size_t)(p - (char*)d_ws);
  // Tier1: Ut z=18 (72 MB bf16 pair) + LB fp32 18 planes (72 MB) -> ~180 MB total.
  size_t needT1 = fixed + (size_t)18 * IMGSZ * 4 /*UtH+UtL bytes*/ + (size_t)18 * IMGSZ * 4;
  bool t1 = ws_size >= needT1;
  int nz = t1 ? 18 : 6;
  u16* UtH = (u16*)p;                       p += (size_t)nz * IMGSZ * 2;
  u16* UtL = (u16*)p;                       p += (size_t)nz * IMGSZ * 2;
  float* LB = (float*)p;  // t1: 18 planes of log-blur; t2: 6-plane fp32 accumulator
  float* pd = taps;       // overlay dead taps region
  float* ps = taps + NB1;

  build_taps_k<<<3, 256, 0, stream>>>(taps);
  for (int s = 0; s < 3; s++)
    build_w_k<<<IMN, 256, 0, stream>>>(taps + s * 1536, kss[s],
                                       WH + (size_t)s * IMGSZ, WL + (size_t)s * IMGSZ);
  split_img_k<<<NIMG * IMGSZ / 1024, 256, 0, stream>>>(inp, imgH, imgL);

  if (t1) {
    dim3 g(8, 8, 18);
    gemm_pass<0><<<g, 256, 0, stream>>>(imgH, imgL, WH, WL, UtH, UtL, nullptr, 0, 0, 0);
    gemm_pass<1><<<g, 256, 0, stream>>>(UtH, UtL, WH, WL, nullptr, nullptr, LB, 0, 1, 0);
  } else {
    dim3 g(8, 8, 6);
    for (int s = 0; s < 3; s++) {
      gemm_pass<0><<<g, 256, 0, stream>>>(imgH, imgL, WH, WL, UtH, UtL, nullptr, s, 0, 0);
      gemm_pass<1><<<g, 256, 0, stream>>>(UtH, UtL, WH, WL, nullptr, nullptr, LB, s, 0, s > 0);
    }
  }
  loss_stage1_k<<<NB1, 256, 0, stream>>>(inp, LB, t1 ? 1 : 0, refl, illum, pd, ps);
  loss_stage2_k<<<1, 256, 0, stream>>>(pd, ps, out);
}